// Round 2
// baseline (466.871 us; speedup 1.0000x reference)
//
#include <hip/hip_runtime.h>
#include <hip/hip_bf16.h>

typedef __bf16 bf16x8 __attribute__((ext_vector_type(8)));
typedef float f32x4 __attribute__((ext_vector_type(4)));

#define GLDS16(gp, lp) \
    __builtin_amdgcn_global_load_lds((__attribute__((address_space(1))) void*)(gp), \
                                     (__attribute__((address_space(3))) void*)(lp), 16, 0, 0)

// Barrier that does NOT drain vmcnt: lets prefetched global loads stay in
// flight across the sync (ds ordering still guaranteed via lgkmcnt(0)).
static __device__ __forceinline__ void bar_nodrain() {
    __builtin_amdgcn_sched_barrier(0);
    asm volatile("s_waitcnt lgkmcnt(0)" ::: "memory");
    __builtin_amdgcn_s_barrier();
    __builtin_amdgcn_sched_barrier(0);
}

// ---------------------------------------------------------------- convert (+ fused bias/energy)
// blocks 0..4095: x (4M floats) and Wq/Wk/Wv/Wo (1M each) -> bf16 copies in ws.
// block 4096: torsion bias vector + energy scalar.
__global__ __launch_bounds__(256) void k_convert(
    const float* __restrict__ x, const float* __restrict__ Wq,
    const float* __restrict__ Wk, const float* __restrict__ Wv,
    const float* __restrict__ Wo,
    __bf16* __restrict__ xb, __bf16* __restrict__ wqb, __bf16* __restrict__ wkb,
    __bf16* __restrict__ wvb, __bf16* __restrict__ wob,
    const float* __restrict__ field, const float* __restrict__ strength,
    float* __restrict__ bias_out, float* __restrict__ energy_out)
{
    if (blockIdx.x == 4096) {
        int t = threadIdx.x;
        #pragma unroll
        for (int m = t; m < 1024; m += 256) {
            float acc = 0.f;
            #pragma unroll
            for (int o = 0; o < 3; ++o) {
                float s  = strength[o];
                float ph = 1.f / (1.f + __expf(-field[o * 1024 + m]));
                float tt = (float)(m * (o + 1)) * 3.14159265358979323846f / 1024.f;
                acc += s * sinf(tt) * ph;
            }
            bias_out[m] = acc;
        }
        if (t == 0) {
            float s0 = strength[0], s1 = strength[1], s2 = strength[2];
            energy_out[0] = (s0 * s0 + s1 * s1 + s2 * s2) * (1.f / 3.f);
        }
        return;
    }
    size_t g = (size_t)blockIdx.x * 256 + threadIdx.x;   // 0 .. 1048575
    size_t e = g * 8;
    const float* src; __bf16* dst; size_t off;
    if (e < 4194304) { src = x; dst = xb; off = e; }
    else {
        size_t t = e - 4194304;
        int w = (int)(t >> 20); off = t & 1048575;
        src = (w == 0 ? Wq : w == 1 ? Wk : w == 2 ? Wv : Wo);
        dst = (w == 0 ? wqb : w == 1 ? wkb : w == 2 ? wvb : wob);
    }
    float4 a = *(const float4*)(src + off);
    float4 b = *(const float4*)(src + off + 4);
    bf16x8 o;
    o[0] = (__bf16)a.x; o[1] = (__bf16)a.y; o[2] = (__bf16)a.z; o[3] = (__bf16)a.w;
    o[4] = (__bf16)b.x; o[5] = (__bf16)b.y; o[6] = (__bf16)b.z; o[7] = (__bf16)b.w;
    *(bf16x8*)(dst + off) = o;
}

// ---------------------------------------------------------------- NT GEMM (m97 recipe)
// C[m][n] = sum_k A[m][k] * Bt[n][k]  (+ bias[n]); M=4096, K=1024, N per grid.
// MODE 0 (BN=128): z in {0,1,2} selects (Wq,bq)->q_ws, (Wk,bk)->k_ws, (Wv,bv)->vT_ws.
// MODE 1 (BN=64): Bt=B0, bias0, fp32 nt out. XCD swizzle clusters m-panels per XCD.
template <int MODE, int BN>
__global__ __launch_bounds__(256) void k_gemm(
    const __bf16* __restrict__ A,
    const __bf16* __restrict__ B0, const __bf16* __restrict__ B1, const __bf16* __restrict__ B2,
    const float* __restrict__ bias0, const float* __restrict__ bias1, const float* __restrict__ bias2,
    __bf16* __restrict__ q_ws, __bf16* __restrict__ k_ws, __bf16* __restrict__ vT_ws,
    float* __restrict__ out)
{
    const int K = 1024;
    constexpr int NB = BN / 32;            // 4 (BN=128) or 2 (BN=64)
    __shared__ __bf16 As[128 * 32];
    __shared__ __bf16 Bs[BN * 32];

    int tid = threadIdx.x;
    int w = tid >> 6, l = tid & 63;
    int l15 = l & 15, quad = l >> 4;

    int bx = blockIdx.x, by = blockIdx.y;
    if constexpr (MODE == 1) {
        // grid (16,32): cluster 4 consecutive m-panels per XCD so the A (O_ws)
        // panel is fetched once per XCD instead of by all 8.
        int lin = by * 16 + bx;            // 0..511, XCD = lin & 7 (round-robin heuristic)
        int xcd = lin & 7, t = lin >> 3;   // t 0..63
        bx = t & 15;
        by = xcd * 4 + (t >> 4);
    }
    int m0 = by * 128, n0 = bx * BN;
    int z = blockIdx.z;

    const __bf16* Bm = (MODE == 1) ? B0 : (z == 0 ? B0 : (z == 1 ? B1 : B2));
    const float*  bv = (MODE == 1) ? bias0 : (z == 0 ? bias0 : (z == 1 ? bias1 : bias2));

    int srow = w * 16 + (l >> 2);
    int scol = (l & 3) * 8;
    const __bf16* gA = A  + (size_t)(m0 + srow) * K + scol;
    const __bf16* gB = Bm + (size_t)(n0 + srow) * K + scol;
    __bf16* lA = As + w * 512;   // wave-uniform LDS base (lane*16B appended by HW)
    __bf16* lB = Bs + w * 512;

    f32x4 zero = {0.f, 0.f, 0.f, 0.f};
    f32x4 acc[4][NB];
    #pragma unroll
    for (int i = 0; i < 4; ++i)
        #pragma unroll
        for (int j = 0; j < NB; ++j) acc[i][j] = zero;

    int wm = w >> 1, wn = w & 1;

    for (int k0 = 0; k0 < K; k0 += 32) {
        __syncthreads();                       // previous tile fully consumed
        GLDS16(gA + k0,           lA);
        GLDS16(gA + 64 * K + k0,  lA + 2048);
        GLDS16(gB + k0,           lB);
        if (BN == 128) GLDS16(gB + 64 * K + k0,  lB + 2048);
        __builtin_amdgcn_s_waitcnt(0);
        __syncthreads();

        bf16x8 af[4], bfr[NB];
        #pragma unroll
        for (int t = 0; t < 4; ++t)
            af[t] = *(const bf16x8*)&As[(wm * 64 + t * 16 + l15) * 32 + quad * 8];
        #pragma unroll
        for (int t = 0; t < NB; ++t)
            bfr[t] = *(const bf16x8*)&Bs[(wn * (BN / 2) + t * 16 + l15) * 32 + quad * 8];
        #pragma unroll
        for (int i = 0; i < 4; ++i)
            #pragma unroll
            for (int j = 0; j < NB; ++j)
                acc[i][j] = __builtin_amdgcn_mfma_f32_16x16x32_bf16(af[i], bfr[j], acc[i][j], 0, 0, 0);
    }

    // epilogue: C row = quad*4+r (m), col = l15 (n) within each 16x16 tile
    #pragma unroll
    for (int i = 0; i < 4; ++i) {
        int mbase = m0 + wm * 64 + i * 16 + quad * 4;
        #pragma unroll
        for (int j = 0; j < NB; ++j) {
            int n = n0 + wn * (BN / 2) + j * 16 + l15;
            float badd = bv[n];
            #pragma unroll
            for (int r = 0; r < 4; ++r) {
                int m = mbase + r;
                float vres = acc[i][j][r] + badd;
                if (MODE == 1) {
                    __builtin_nontemporal_store(vres, &out[(size_t)m * 1024 + n]);
                } else {
                    int b = m >> 10, lpos = m & 1023, h = n >> 6, d = n & 63;
                    if (z == 2)
                        vT_ws[(((size_t)(b * 16 + h)) * 64 + d) * 1024 + lpos] = (__bf16)vres;
                    else {
                        __bf16* dst = (z == 0 ? q_ws : k_ws);
                        dst[(((size_t)(b * 16 + h)) * 1024 + lpos) * 64 + d] = (__bf16)vres;
                    }
                }
            }
        }
    }
}

// ---------------------------------------------------------------- attention
// grid (8 row-blocks, 64 bh); block 256 (4 waves, 2x2).
// XCD swizzle: each XCD owns 8 whole bh's (8 row-blocks each) so K/V re-reads
// are per-XCD L2 hits (1.5 MB per XCD << 4 MB L2).
// pass 0: S=qK^T/8+bias -> p=exp -> rowsum(reg), P_s->LDS, O += P@V (unnormalized)
// pass 1: recompute S -> write attn = p * rowinv (nt stores: stream, don't evict K/V)
__global__ __launch_bounds__(256, 2) void k_attn(
    const __bf16* __restrict__ qg, const __bf16* __restrict__ kg, const __bf16* __restrict__ vTg,
    const float* __restrict__ bias, float* __restrict__ attn, __bf16* __restrict__ Og)
{
    __shared__ __bf16 q_s[128 * 72];
    __shared__ __bf16 K_s[64 * 72];
    __shared__ __bf16 Vt_s[64 * 72];
    __shared__ __bf16 P_s[128 * 72];
    __shared__ float bias_s[1024];
    __shared__ float rowsum[128];
    __shared__ float rowinv[128];

    int tid = threadIdx.x, w = tid >> 6, l = tid & 63;
    int l15 = l & 15, quad = l >> 4;
    int wm = w >> 1, wn = w & 1;

    // XCD-clustered work assignment (bijective remap of (x,y))
    int lin = blockIdx.y * 8 + blockIdx.x;   // 0..511, XCD = lin & 7 heuristic
    int xcd = lin & 7, t = lin >> 3;         // t 0..63
    int bh  = xcd * 8 + (t >> 3);            // 8 bh per XCD
    int m0  = (t & 7) * 128;                 // 8 row-blocks per bh

    {   // q block 128x64 -> padded LDS (stride 72 breaks bank-aliasing)
        const __bf16* src = qg + ((size_t)bh * 1024 + m0) * 64;
        for (int i = tid; i < 1024; i += 256) {
            int r = i >> 3, c = (i & 7) * 8;
            *(int4*)&q_s[r * 72 + c] = *(const int4*)&src[(size_t)r * 64 + c];
        }
    }
    *(float4*)&bias_s[tid * 4] = *(const float4*)&bias[tid * 4];
    if (tid < 128) rowsum[tid] = 0.f;

    // staging coords: this thread owns K/V rows sr and sr+32, 16B at col sc
    int sr = tid >> 3;            // 0..31
    int sc = (tid & 7) * 8;       // 0..56
    const __bf16* kbase = kg  + (size_t)bh * 1024 * 64;
    const __bf16* vbase = vTg + (size_t)bh * 64 * 1024;

    // prefetch chunk 0
    int4 kr0 = *(const int4*)&kbase[(size_t)(sr)      * 64 + sc];
    int4 kr1 = *(const int4*)&kbase[(size_t)(sr + 32) * 64 + sc];
    int4 vr0 = *(const int4*)&vbase[(size_t)(sr)      * 1024 + sc];
    int4 vr1 = *(const int4*)&vbase[(size_t)(sr + 32) * 1024 + sc];

    f32x4 zero = {0.f, 0.f, 0.f, 0.f};
    f32x4 accO[4][2];
    #pragma unroll
    for (int i = 0; i < 4; ++i) { accO[i][0] = zero; accO[i][1] = zero; }
    float rs[4][4];
    #pragma unroll
    for (int i = 0; i < 4; ++i)
        #pragma unroll
        for (int r = 0; r < 4; ++r) rs[i][r] = 0.f;

    for (int pass = 0; pass < 2; ++pass) {
        for (int ch = 0; ch < 16; ++ch) {
            int n0c = ch * 64;
            bar_nodrain();   // prev chunk's LDS reads complete (also covers q_s init)
            *(int4*)&K_s[sr * 72 + sc]        = kr0;
            *(int4*)&K_s[(sr + 32) * 72 + sc] = kr1;
            if (pass == 0) {
                *(int4*)&Vt_s[sr * 72 + sc]        = vr0;
                *(int4*)&Vt_s[(sr + 32) * 72 + sc] = vr1;
            }
            bar_nodrain();   // staged data visible to all waves

            // issue next chunk's loads; they fly under this chunk's compute
            if (ch < 15) {
                int nn = n0c + 64;
                kr0 = *(const int4*)&kbase[(size_t)(nn + sr)      * 64 + sc];
                kr1 = *(const int4*)&kbase[(size_t)(nn + sr + 32) * 64 + sc];
                if (pass == 0) {
                    vr0 = *(const int4*)&vbase[(size_t)(sr)      * 1024 + nn + sc];
                    vr1 = *(const int4*)&vbase[(size_t)(sr + 32) * 1024 + nn + sc];
                }
            } else if (pass == 0) {   // prefetch pass-1 chunk 0 (K only)
                kr0 = *(const int4*)&kbase[(size_t)(sr)      * 64 + sc];
                kr1 = *(const int4*)&kbase[(size_t)(sr + 32) * 64 + sc];
            }

            f32x4 accS[4][2];
            #pragma unroll
            for (int i = 0; i < 4; ++i) { accS[i][0] = zero; accS[i][1] = zero; }
            __builtin_amdgcn_s_setprio(1);
            #pragma unroll
            for (int ks2 = 0; ks2 < 2; ++ks2) {
                bf16x8 af[4], bfr[2];
                #pragma unroll
                for (int t2 = 0; t2 < 4; ++t2)
                    af[t2] = *(const bf16x8*)&q_s[(wm * 64 + t2 * 16 + l15) * 72 + ks2 * 32 + quad * 8];
                #pragma unroll
                for (int t2 = 0; t2 < 2; ++t2)
                    bfr[t2] = *(const bf16x8*)&K_s[(wn * 32 + t2 * 16 + l15) * 72 + ks2 * 32 + quad * 8];
                #pragma unroll
                for (int i = 0; i < 4; ++i)
                    #pragma unroll
                    for (int j = 0; j < 2; ++j)
                        accS[i][j] = __builtin_amdgcn_mfma_f32_16x16x32_bf16(af[i], bfr[j], accS[i][j], 0, 0, 0);
            }
            __builtin_amdgcn_s_setprio(0);

            float p[4][2][4];
            #pragma unroll
            for (int i = 0; i < 4; ++i)
                #pragma unroll
                for (int j = 0; j < 2; ++j) {
                    float bcol = bias_s[n0c + wn * 32 + j * 16 + l15];
                    #pragma unroll
                    for (int r = 0; r < 4; ++r)
                        p[i][j][r] = __expf(0.125f * accS[i][j][r] + bcol);
                }

            if (pass == 0) {
                #pragma unroll
                for (int i = 0; i < 4; ++i)
                    #pragma unroll
                    for (int r = 0; r < 4; ++r)
                        rs[i][r] += p[i][0][r] + p[i][1][r];   // reduce once after loop
                #pragma unroll
                for (int i = 0; i < 4; ++i)
                    #pragma unroll
                    for (int j = 0; j < 2; ++j)
                        #pragma unroll
                        for (int r = 0; r < 4; ++r)
                            P_s[(wm * 64 + i * 16 + quad * 4 + r) * 72 + wn * 32 + j * 16 + l15] =
                                (__bf16)p[i][j][r];
                bar_nodrain();
                // O += P(128x64) @ V(64x64)
                __builtin_amdgcn_s_setprio(1);
                #pragma unroll
                for (int ks2 = 0; ks2 < 2; ++ks2) {
                    bf16x8 af[4], bfr[2];
                    #pragma unroll
                    for (int t2 = 0; t2 < 4; ++t2)
                        af[t2] = *(const bf16x8*)&P_s[(wm * 64 + t2 * 16 + l15) * 72 + ks2 * 32 + quad * 8];
                    #pragma unroll
                    for (int t2 = 0; t2 < 2; ++t2)
                        bfr[t2] = *(const bf16x8*)&Vt_s[(wn * 32 + t2 * 16 + l15) * 72 + ks2 * 32 + quad * 8];
                    #pragma unroll
                    for (int i = 0; i < 4; ++i)
                        #pragma unroll
                        for (int j = 0; j < 2; ++j)
                            accO[i][j] = __builtin_amdgcn_mfma_f32_16x16x32_bf16(af[i], bfr[j], accO[i][j], 0, 0, 0);
                }
                __builtin_amdgcn_s_setprio(0);
            } else {
                float* dst = attn + ((size_t)bh << 20) + (size_t)m0 * 1024;
                #pragma unroll
                for (int i = 0; i < 4; ++i)
                    #pragma unroll
                    for (int r = 0; r < 4; ++r) {
                        int row = wm * 64 + i * 16 + quad * 4 + r;
                        float inv = rowinv[row];
                        #pragma unroll
                        for (int j = 0; j < 2; ++j) {
                            int col = n0c + wn * 32 + j * 16 + l15;
                            __builtin_nontemporal_store(p[i][j][r] * inv,
                                                        &dst[(size_t)row * 1024 + col]);
                        }
                    }
            }
        }
        if (pass == 0) {
            // single rowsum reduction for all 16 chunks
            #pragma unroll
            for (int i = 0; i < 4; ++i)
                #pragma unroll
                for (int r = 0; r < 4; ++r) {
                    float s = rs[i][r];
                    s += __shfl_xor(s, 1, 16);
                    s += __shfl_xor(s, 2, 16);
                    s += __shfl_xor(s, 4, 16);
                    s += __shfl_xor(s, 8, 16);
                    if (l15 == 0) atomicAdd(&rowsum[wm * 64 + i * 16 + quad * 4 + r], s);
                }
            bar_nodrain();
            if (tid < 128) rowinv[tid] = 1.f / rowsum[tid];
            bar_nodrain();
            int b = bh >> 4, h = bh & 15;
            #pragma unroll
            for (int i = 0; i < 4; ++i)
                #pragma unroll
                for (int r = 0; r < 4; ++r) {
                    int row = wm * 64 + i * 16 + quad * 4 + r;
                    float inv = rowinv[row];
                    #pragma unroll
                    for (int j = 0; j < 2; ++j) {
                        int d = wn * 32 + j * 16 + l15;
                        Og[((size_t)(b * 1024 + m0 + row)) * 1024 + h * 64 + d] =
                            (__bf16)(accO[i][j][r] * inv);
                    }
                }
        }
    }
}

// ---------------------------------------------------------------- launch
extern "C" void kernel_launch(void* const* d_in, const int* in_sizes, int n_in,
                              void* d_out, int out_size, void* d_ws, size_t ws_size,
                              hipStream_t stream)
{
    const float* x  = (const float*)d_in[0];
    const float* Wq = (const float*)d_in[1];
    const float* bq = (const float*)d_in[2];
    const float* Wk = (const float*)d_in[3];
    const float* bk = (const float*)d_in[4];
    const float* Wv = (const float*)d_in[5];
    const float* bvv= (const float*)d_in[6];
    const float* Wo = (const float*)d_in[7];
    const float* bo = (const float*)d_in[8];
    const float* tf = (const float*)d_in[9];
    const float* ts = (const float*)d_in[10];

    float* out    = (float*)d_out;
    float* attn   = out + 4194304;           // (4,16,1024,1024)
    float* energy = attn + 67108864;         // scalar

    char* ws = (char*)d_ws;
    float*  bias  = (float*)ws;                                   //   4 KB
    __bf16* xb    = (__bf16*)(ws + 4096);                         // 8.4 MB (reused as O_ws)
    __bf16* wqb   = (__bf16*)(ws + 4096 + 8388608);               //   2 MB
    __bf16* wkb   = wqb + 1048576;
    __bf16* wvb   = wkb + 1048576;
    __bf16* wob   = wvb + 1048576;
    __bf16* q_ws  = wob + 1048576;                                // 8.4 MB
    __bf16* k_ws  = q_ws + 4194304;                               // 8.4 MB
    __bf16* vT_ws = k_ws + 4194304;                               // 8.4 MB
    __bf16* O_ws  = xb;   // x_bf dead after projections; reuse for O

    k_convert<<<dim3(4097), dim3(256), 0, stream>>>(x, Wq, Wk, Wv, Wo, xb, wqb, wkb, wvb, wob,
                                                    tf, ts, bias, energy);
    k_gemm<0, 128><<<dim3(8, 32, 3), dim3(256), 0, stream>>>(xb, wqb, wkb, wvb, bq, bk, bvv,
                                                             q_ws, k_ws, vT_ws, nullptr);
    k_attn<<<dim3(8, 64), dim3(256), 0, stream>>>(q_ws, k_ws, vT_ws, bias, attn, O_ws);
    k_gemm<1, 64><<<dim3(16, 32, 1), dim3(256), 0, stream>>>(O_ws, wob, nullptr, nullptr, bo,
                                                             nullptr, nullptr, nullptr, nullptr,
                                                             nullptr, out);
}

// Round 5
// 431.015 us; speedup vs baseline: 1.0832x; 1.0832x over previous
//
#include <hip/hip_runtime.h>
#include <hip/hip_bf16.h>

typedef __bf16 bf16x8 __attribute__((ext_vector_type(8)));
typedef __bf16 bf16x4 __attribute__((ext_vector_type(4)));
typedef float f32x4 __attribute__((ext_vector_type(4)));

#define GLDS16(gp, lp) \
    __builtin_amdgcn_global_load_lds((__attribute__((address_space(1))) void*)(gp), \
                                     (__attribute__((address_space(3))) void*)(lp), 16, 0, 0)

// Barrier that does NOT drain vmcnt: lets prefetched global loads stay in
// flight across the sync (ds ordering still guaranteed via lgkmcnt(0)).
static __device__ __forceinline__ void bar_nodrain() {
    __builtin_amdgcn_sched_barrier(0);
    asm volatile("s_waitcnt lgkmcnt(0)" ::: "memory");
    __builtin_amdgcn_s_barrier();
    __builtin_amdgcn_sched_barrier(0);
}

// ---------------------------------------------------------------- convert (+ fused bias/energy)
// blocks 0..4095: x (4M floats) and Wq/Wk/Wv/Wo (1M each) -> bf16 copies in ws.
// block 4096: torsion bias vector + energy scalar.
__global__ __launch_bounds__(256) void k_convert(
    const float* __restrict__ x, const float* __restrict__ Wq,
    const float* __restrict__ Wk, const float* __restrict__ Wv,
    const float* __restrict__ Wo,
    __bf16* __restrict__ xb, __bf16* __restrict__ wqb, __bf16* __restrict__ wkb,
    __bf16* __restrict__ wvb, __bf16* __restrict__ wob,
    const float* __restrict__ field, const float* __restrict__ strength,
    float* __restrict__ bias_out, float* __restrict__ energy_out)
{
    if (blockIdx.x == 4096) {
        int t = threadIdx.x;
        #pragma unroll
        for (int m = t; m < 1024; m += 256) {
            float acc = 0.f;
            #pragma unroll
            for (int o = 0; o < 3; ++o) {
                float s  = strength[o];
                float ph = 1.f / (1.f + __expf(-field[o * 1024 + m]));
                float tt = (float)(m * (o + 1)) * 3.14159265358979323846f / 1024.f;
                acc += s * sinf(tt) * ph;
            }
            bias_out[m] = acc;
        }
        if (t == 0) {
            float s0 = strength[0], s1 = strength[1], s2 = strength[2];
            energy_out[0] = (s0 * s0 + s1 * s1 + s2 * s2) * (1.f / 3.f);
        }
        return;
    }
    size_t g = (size_t)blockIdx.x * 256 + threadIdx.x;   // 0 .. 1048575
    size_t e = g * 8;
    const float* src; __bf16* dst; size_t off;
    if (e < 4194304) { src = x; dst = xb; off = e; }
    else {
        size_t t = e - 4194304;
        int w = (int)(t >> 20); off = t & 1048575;
        src = (w == 0 ? Wq : w == 1 ? Wk : w == 2 ? Wv : Wo);
        dst = (w == 0 ? wqb : w == 1 ? wkb : w == 2 ? wvb : wob);
    }
    float4 a = *(const float4*)(src + off);
    float4 b = *(const float4*)(src + off + 4);
    bf16x8 o;
    o[0] = (__bf16)a.x; o[1] = (__bf16)a.y; o[2] = (__bf16)a.z; o[3] = (__bf16)a.w;
    o[4] = (__bf16)b.x; o[5] = (__bf16)b.y; o[6] = (__bf16)b.z; o[7] = (__bf16)b.w;
    *(bf16x8*)(dst + off) = o;
}

// ---------------------------------------------------------------- NT GEMM (m97 recipe)
// C[m][n] = sum_k A[m][k] * Bt[n][k]  (+ bias[n]); M=4096, K=1024, N per grid.
// MODE 0 (BN=128): z in {0,1,2} selects (Wq,bq)->q_ws, (Wk,bk)->k_ws, (Wv,bv)->vT_ws.
//   z==2 routes the C-tile through LDS (Cs) so the transposed vT write is
//   coalesced dwordx4 instead of a 2B-per-lane stride-2KB scatter.
// MODE 1 (BN=64): Bt=B0, bias0, fp32 out; grid (16,32) -> 2 blocks/CU.
template <int MODE, int BN>
__global__ __launch_bounds__(256) void k_gemm(
    const __bf16* __restrict__ A,
    const __bf16* __restrict__ B0, const __bf16* __restrict__ B1, const __bf16* __restrict__ B2,
    const float* __restrict__ bias0, const float* __restrict__ bias1, const float* __restrict__ bias2,
    __bf16* __restrict__ q_ws, __bf16* __restrict__ k_ws, __bf16* __restrict__ vT_ws,
    float* __restrict__ out)
{
    const int K = 1024;
    constexpr int NB = BN / 32;            // 4 (BN=128) or 2 (BN=64)
    __shared__ __bf16 As[128 * 32];
    __shared__ __bf16 Bs[BN * 32];
    __shared__ __bf16 Cs[MODE == 0 ? 128 * 136 : 4];   // z==2 transpose staging

    int tid = threadIdx.x;
    int w = tid >> 6, l = tid & 63;
    int l15 = l & 15, quad = l >> 4;
    int m0 = blockIdx.y * 128, n0 = blockIdx.x * BN;
    int z = blockIdx.z;

    const __bf16* Bm = (MODE == 1) ? B0 : (z == 0 ? B0 : (z == 1 ? B1 : B2));
    const float*  bv = (MODE == 1) ? bias0 : (z == 0 ? bias0 : (z == 1 ? bias1 : bias2));

    int srow = w * 16 + (l >> 2);
    int scol = (l & 3) * 8;
    const __bf16* gA = A  + (size_t)(m0 + srow) * K + scol;
    const __bf16* gB = Bm + (size_t)(n0 + srow) * K + scol;
    __bf16* lA = As + w * 512;   // wave-uniform LDS base (lane*16B appended by HW)
    __bf16* lB = Bs + w * 512;

    f32x4 zero = {0.f, 0.f, 0.f, 0.f};
    f32x4 acc[4][NB];
    #pragma unroll
    for (int i = 0; i < 4; ++i)
        #pragma unroll
        for (int j = 0; j < NB; ++j) acc[i][j] = zero;

    int wm = w >> 1, wn = w & 1;

    for (int k0 = 0; k0 < K; k0 += 32) {
        __syncthreads();                       // previous tile fully consumed
        GLDS16(gA + k0,           lA);
        GLDS16(gA + 64 * K + k0,  lA + 2048);
        GLDS16(gB + k0,           lB);
        if (BN == 128) GLDS16(gB + 64 * K + k0,  lB + 2048);
        __builtin_amdgcn_s_waitcnt(0);
        __syncthreads();

        bf16x8 af[4], bfr[NB];
        #pragma unroll
        for (int t = 0; t < 4; ++t)
            af[t] = *(const bf16x8*)&As[(wm * 64 + t * 16 + l15) * 32 + quad * 8];
        #pragma unroll
        for (int t = 0; t < NB; ++t)
            bfr[t] = *(const bf16x8*)&Bs[(wn * (BN / 2) + t * 16 + l15) * 32 + quad * 8];
        #pragma unroll
        for (int i = 0; i < 4; ++i)
            #pragma unroll
            for (int j = 0; j < NB; ++j)
                acc[i][j] = __builtin_amdgcn_mfma_f32_16x16x32_bf16(af[i], bfr[j], acc[i][j], 0, 0, 0);
    }

    if constexpr (MODE == 0) {
        if (z == 2) {
            // C fragment: row = m (quad*4+r), col = n (l15). Pack each lane's
            // 4 consecutive m into one b64 LDS write at Cs[n][m].
            #pragma unroll
            for (int j = 0; j < NB; ++j) {
                int nl = wn * 64 + j * 16 + l15;
                float badd = bv[n0 + nl];
                #pragma unroll
                for (int i = 0; i < 4; ++i) {
                    int ml = wm * 64 + i * 16 + quad * 4;
                    bf16x4 cv;
                    #pragma unroll
                    for (int r = 0; r < 4; ++r) cv[r] = (__bf16)(acc[i][j][r] + badd);
                    *(bf16x4*)&Cs[nl * 136 + ml] = cv;
                }
            }
            __syncthreads();
            // stream out: one (d, m-half) row per thread, 8 x dwordx4
            int row = tid >> 1;              // n_local 0..127
            int mh  = (tid & 1) * 64;        // m half
            int n = n0 + row, h = n >> 6, d = n & 63;
            int b = m0 >> 10;
            int lpos0 = m0 & 1023;           // position within the 1024-long L axis
            __bf16* drow = vT_ws + (((size_t)(b * 16 + h)) * 64 + d) * 1024 + lpos0 + mh;
            #pragma unroll
            for (int s2 = 0; s2 < 8; ++s2)
                *(int4*)&drow[s2 * 8] = *(const int4*)&Cs[row * 136 + mh + s2 * 8];
            return;
        }
    }

    // epilogue: C row = quad*4+r (m), col = l15 (n) within each 16x16 tile
    #pragma unroll
    for (int i = 0; i < 4; ++i) {
        int mbase = m0 + wm * 64 + i * 16 + quad * 4;
        #pragma unroll
        for (int j = 0; j < NB; ++j) {
            int n = n0 + wn * (BN / 2) + j * 16 + l15;
            float badd = bv[n];
            #pragma unroll
            for (int r = 0; r < 4; ++r) {
                int m = mbase + r;
                float vres = acc[i][j][r] + badd;
                if (MODE == 1) {
                    out[(size_t)m * 1024 + n] = vres;
                } else {
                    int b = m >> 10, lpos = m & 1023, h = n >> 6, d = n & 63;
                    __bf16* dst = (z == 0 ? q_ws : k_ws);
                    dst[(((size_t)(b * 16 + h)) * 1024 + lpos) * 64 + d] = (__bf16)vres;
                }
            }
        }
    }
}

// ---------------------------------------------------------------- attention
// grid (8 row-blocks, 64 bh); block 256 (4 waves, 2x2).
// SWAPPED QK^T: accT[j][i] = mfma(Kfrag, Qfrag) computes S^T fragments, so a
// lane holds 4 CONSECUTIVE kv for one q row -> b64 P_s writes, dwordx4 attn
// stores, float4 bias loads. Same arithmetic, same LDS reads as unswapped.
// pass 0: S -> p=exp -> rowsum(reg), P_s->LDS, O += P@V (unnormalized)
// pass 1: recompute S -> write attn = p * rowinv (once, 268 MB, coalesced)
__global__ __launch_bounds__(256, 2) void k_attn(
    const __bf16* __restrict__ qg, const __bf16* __restrict__ kg, const __bf16* __restrict__ vTg,
    const float* __restrict__ bias, float* __restrict__ attn, __bf16* __restrict__ Og)
{
    __shared__ __bf16 q_s[128 * 72];
    __shared__ __bf16 K_s[64 * 72];
    __shared__ __bf16 Vt_s[64 * 72];
    __shared__ __bf16 P_s[128 * 72];
    __shared__ float bias_s[1024];
    __shared__ float rowsum[128];
    __shared__ float rowinv[128];

    int tid = threadIdx.x, w = tid >> 6, l = tid & 63;
    int l15 = l & 15, quad = l >> 4;
    int wm = w >> 1, wn = w & 1;
    int bh = blockIdx.y;
    int m0 = blockIdx.x * 128;

    {   // q block 128x64 -> padded LDS (stride 72 breaks bank-aliasing)
        const __bf16* src = qg + ((size_t)bh * 1024 + m0) * 64;
        for (int i = tid; i < 1024; i += 256) {
            int r = i >> 3, c = (i & 7) * 8;
            *(int4*)&q_s[r * 72 + c] = *(const int4*)&src[(size_t)r * 64 + c];
        }
    }
    *(float4*)&bias_s[tid * 4] = *(const float4*)&bias[tid * 4];
    if (tid < 128) rowsum[tid] = 0.f;

    // staging coords: this thread owns K/V rows sr and sr+32, 16B at col sc
    int sr = tid >> 3;            // 0..31
    int sc = (tid & 7) * 8;       // 0..56
    const __bf16* kbase = kg  + (size_t)bh * 1024 * 64;
    const __bf16* vbase = vTg + (size_t)bh * 64 * 1024;

    // prefetch chunk 0
    int4 kr0 = *(const int4*)&kbase[(size_t)(sr)      * 64 + sc];
    int4 kr1 = *(const int4*)&kbase[(size_t)(sr + 32) * 64 + sc];
    int4 vr0 = *(const int4*)&vbase[(size_t)(sr)      * 1024 + sc];
    int4 vr1 = *(const int4*)&vbase[(size_t)(sr + 32) * 1024 + sc];

    f32x4 zero = {0.f, 0.f, 0.f, 0.f};
    f32x4 accO[4][2];
    #pragma unroll
    for (int i = 0; i < 4; ++i) { accO[i][0] = zero; accO[i][1] = zero; }
    float rs[4];
    #pragma unroll
    for (int i = 0; i < 4; ++i) rs[i] = 0.f;

    for (int pass = 0; pass < 2; ++pass) {
        for (int ch = 0; ch < 16; ++ch) {
            int n0c = ch * 64;
            bar_nodrain();   // prev chunk's LDS reads complete (also covers q_s init)
            *(int4*)&K_s[sr * 72 + sc]        = kr0;
            *(int4*)&K_s[(sr + 32) * 72 + sc] = kr1;
            if (pass == 0) {
                *(int4*)&Vt_s[sr * 72 + sc]        = vr0;
                *(int4*)&Vt_s[(sr + 32) * 72 + sc] = vr1;
            }
            bar_nodrain();   // staged data visible to all waves

            // issue next chunk's loads; they fly under this chunk's compute
            if (ch < 15) {
                int nn = n0c + 64;
                kr0 = *(const int4*)&kbase[(size_t)(nn + sr)      * 64 + sc];
                kr1 = *(const int4*)&kbase[(size_t)(nn + sr + 32) * 64 + sc];
                if (pass == 0) {
                    vr0 = *(const int4*)&vbase[(size_t)(sr)      * 1024 + nn + sc];
                    vr1 = *(const int4*)&vbase[(size_t)(sr + 32) * 1024 + nn + sc];
                }
            } else if (pass == 0) {   // prefetch pass-1 chunk 0 (K only)
                kr0 = *(const int4*)&kbase[(size_t)(sr)      * 64 + sc];
                kr1 = *(const int4*)&kbase[(size_t)(sr + 32) * 64 + sc];
            }

            // S^T fragments: rows = kv, cols(lanes) = q
            f32x4 accT[2][4];
            #pragma unroll
            for (int j = 0; j < 2; ++j)
                #pragma unroll
                for (int i = 0; i < 4; ++i) accT[j][i] = zero;
            __builtin_amdgcn_s_setprio(1);
            #pragma unroll
            for (int ks2 = 0; ks2 < 2; ++ks2) {
                bf16x8 qf[4], kf[2];
                #pragma unroll
                for (int t2 = 0; t2 < 4; ++t2)
                    qf[t2] = *(const bf16x8*)&q_s[(wm * 64 + t2 * 16 + l15) * 72 + ks2 * 32 + quad * 8];
                #pragma unroll
                for (int t2 = 0; t2 < 2; ++t2)
                    kf[t2] = *(const bf16x8*)&K_s[(wn * 32 + t2 * 16 + l15) * 72 + ks2 * 32 + quad * 8];
                #pragma unroll
                for (int j = 0; j < 2; ++j)
                    #pragma unroll
                    for (int i = 0; i < 4; ++i)
                        accT[j][i] = __builtin_amdgcn_mfma_f32_16x16x32_bf16(kf[j], qf[i], accT[j][i], 0, 0, 0);
            }
            __builtin_amdgcn_s_setprio(0);

            // bias along kv is now the register (row) axis: vector loads
            f32x4 b4[2];
            #pragma unroll
            for (int j = 0; j < 2; ++j)
                b4[j] = *(const f32x4*)&bias_s[n0c + wn * 32 + j * 16 + quad * 4];

            float p[4][2][4];   // [i=q-block][j=kv-block][r=kv within quad]
            #pragma unroll
            for (int i = 0; i < 4; ++i)
                #pragma unroll
                for (int j = 0; j < 2; ++j)
                    #pragma unroll
                    for (int r = 0; r < 4; ++r)
                        p[i][j][r] = __expf(0.125f * accT[j][i][r] + b4[j][r]);

            if (pass == 0) {
                #pragma unroll
                for (int i = 0; i < 4; ++i)
                    #pragma unroll
                    for (int j = 0; j < 2; ++j)
                        #pragma unroll
                        for (int r = 0; r < 4; ++r)
                            rs[i] += p[i][j][r];   // per-lane partial, reduce after loop
                #pragma unroll
                for (int i = 0; i < 4; ++i)
                    #pragma unroll
                    for (int j = 0; j < 2; ++j) {
                        bf16x4 pv;
                        #pragma unroll
                        for (int r = 0; r < 4; ++r) pv[r] = (__bf16)p[i][j][r];
                        *(bf16x4*)&P_s[(wm * 64 + i * 16 + l15) * 72 + wn * 32 + j * 16 + quad * 4] = pv;
                    }
                bar_nodrain();
                // O += P(128x64) @ V(64x64)
                __builtin_amdgcn_s_setprio(1);
                #pragma unroll
                for (int ks2 = 0; ks2 < 2; ++ks2) {
                    bf16x8 af[4], bfr[2];
                    #pragma unroll
                    for (int t2 = 0; t2 < 4; ++t2)
                        af[t2] = *(const bf16x8*)&P_s[(wm * 64 + t2 * 16 + l15) * 72 + ks2 * 32 + quad * 8];
                    #pragma unroll
                    for (int t2 = 0; t2 < 2; ++t2)
                        bfr[t2] = *(const bf16x8*)&Vt_s[(wn * 32 + t2 * 16 + l15) * 72 + ks2 * 32 + quad * 8];
                    #pragma unroll
                    for (int i = 0; i < 4; ++i)
                        #pragma unroll
                        for (int j = 0; j < 2; ++j)
                            accO[i][j] = __builtin_amdgcn_mfma_f32_16x16x32_bf16(af[i], bfr[j], accO[i][j], 0, 0, 0);
                }
                __builtin_amdgcn_s_setprio(0);
            } else {
                float* dst = attn + ((size_t)bh << 20) + (size_t)m0 * 1024;
                #pragma unroll
                for (int i = 0; i < 4; ++i) {
                    int q = wm * 64 + i * 16 + l15;
                    float inv = rowinv[q];
                    #pragma unroll
                    for (int j = 0; j < 2; ++j) {
                        float4 v;
                        v.x = p[i][j][0] * inv; v.y = p[i][j][1] * inv;
                        v.z = p[i][j][2] * inv; v.w = p[i][j][3] * inv;
                        *(float4*)&dst[(size_t)q * 1024 + n0c + wn * 32 + j * 16 + quad * 4] = v;
                    }
                }
            }
        }
        if (pass == 0) {
            // single rowsum reduction for all 16 chunks (sum across quads)
            #pragma unroll
            for (int i = 0; i < 4; ++i) {
                float s = rs[i];
                s += __shfl_xor(s, 16);
                s += __shfl_xor(s, 32);
                if (quad == 0) atomicAdd(&rowsum[wm * 64 + i * 16 + l15], s);
            }
            bar_nodrain();
            if (tid < 128) rowinv[tid] = 1.f / rowsum[tid];
            bar_nodrain();
            int b = bh >> 4, h = bh & 15;
            #pragma unroll
            for (int i = 0; i < 4; ++i)
                #pragma unroll
                for (int r = 0; r < 4; ++r) {
                    int row = wm * 64 + i * 16 + quad * 4 + r;
                    float inv = rowinv[row];
                    #pragma unroll
                    for (int j = 0; j < 2; ++j) {
                        int d = wn * 32 + j * 16 + l15;
                        Og[((size_t)(b * 1024 + m0 + row)) * 1024 + h * 64 + d] =
                            (__bf16)(accO[i][j][r] * inv);
                    }
                }
        }
    }
}

// ---------------------------------------------------------------- launch
extern "C" void kernel_launch(void* const* d_in, const int* in_sizes, int n_in,
                              void* d_out, int out_size, void* d_ws, size_t ws_size,
                              hipStream_t stream)
{
    const float* x  = (const float*)d_in[0];
    const float* Wq = (const float*)d_in[1];
    const float* bq = (const float*)d_in[2];
    const float* Wk = (const float*)d_in[3];
    const float* bk = (const float*)d_in[4];
    const float* Wv = (const float*)d_in[5];
    const float* bvv= (const float*)d_in[6];
    const float* Wo = (const float*)d_in[7];
    const float* bo = (const float*)d_in[8];
    const float* tf = (const float*)d_in[9];
    const float* ts = (const float*)d_in[10];

    float* out    = (float*)d_out;
    float* attn   = out + 4194304;           // (4,16,1024,1024)
    float* energy = attn + 67108864;         // scalar

    char* ws = (char*)d_ws;
    float*  bias  = (float*)ws;                                   //   4 KB
    __bf16* xb    = (__bf16*)(ws + 4096);                         // 8.4 MB (reused as O_ws)
    __bf16* wqb   = (__bf16*)(ws + 4096 + 8388608);               //   2 MB
    __bf16* wkb   = wqb + 1048576;
    __bf16* wvb   = wkb + 1048576;
    __bf16* wob   = wvb + 1048576;
    __bf16* q_ws  = wob + 1048576;                                // 8.4 MB
    __bf16* k_ws  = q_ws + 4194304;                               // 8.4 MB
    __bf16* vT_ws = k_ws + 4194304;                               // 8.4 MB
    __bf16* O_ws  = xb;   // x_bf dead after projections; reuse for O

    k_convert<<<dim3(4097), dim3(256), 0, stream>>>(x, Wq, Wk, Wv, Wo, xb, wqb, wkb, wvb, wob,
                                                    tf, ts, bias, energy);
    k_gemm<0, 128><<<dim3(8, 32, 3), dim3(256), 0, stream>>>(xb, wqb, wkb, wvb, bq, bk, bvv,
                                                             q_ws, k_ws, vT_ws, nullptr);
    k_attn<<<dim3(8, 64), dim3(256), 0, stream>>>(q_ws, k_ws, vT_ws, bias, attn, O_ws);
    k_gemm<1, 64><<<dim3(16, 32, 1), dim3(256), 0, stream>>>(O_ws, wob, nullptr, nullptr, bo,
                                                             nullptr, nullptr, nullptr, nullptr,
                                                             nullptr, out);
}

// Round 6
// 427.967 us; speedup vs baseline: 1.0909x; 1.0071x over previous
//
#include <hip/hip_runtime.h>
#include <hip/hip_bf16.h>

typedef __bf16 bf16x8 __attribute__((ext_vector_type(8)));
typedef __bf16 bf16x4 __attribute__((ext_vector_type(4)));
typedef float f32x4 __attribute__((ext_vector_type(4)));

#define GLDS16(gp, lp) \
    __builtin_amdgcn_global_load_lds((__attribute__((address_space(1))) void*)(gp), \
                                     (__attribute__((address_space(3))) void*)(lp), 16, 0, 0)

// Barrier that does NOT drain vmcnt: lets prefetched global loads stay in
// flight across the sync (ds ordering still guaranteed via lgkmcnt(0)).
static __device__ __forceinline__ void bar_nodrain() {
    __builtin_amdgcn_sched_barrier(0);
    asm volatile("s_waitcnt lgkmcnt(0)" ::: "memory");
    __builtin_amdgcn_s_barrier();
    __builtin_amdgcn_sched_barrier(0);
}

// Barrier that waits for THIS wave's outstanding global(_load_lds) ops, then
// syncs: after it, every wave's staged LDS data is visible to all.
static __device__ __forceinline__ void bar_wait_vm() {
    __builtin_amdgcn_sched_barrier(0);
    asm volatile("s_waitcnt vmcnt(0)" ::: "memory");
    __builtin_amdgcn_s_barrier();
    __builtin_amdgcn_sched_barrier(0);
}

// ---------------------------------------------------------------- convert (+ fused bias/energy)
// blocks 0..4095: x (4M floats) and Wq/Wk/Wv/Wo (1M each) -> bf16 copies in ws.
// block 4096: torsion bias vector + energy scalar.
__global__ __launch_bounds__(256) void k_convert(
    const float* __restrict__ x, const float* __restrict__ Wq,
    const float* __restrict__ Wk, const float* __restrict__ Wv,
    const float* __restrict__ Wo,
    __bf16* __restrict__ xb, __bf16* __restrict__ wqb, __bf16* __restrict__ wkb,
    __bf16* __restrict__ wvb, __bf16* __restrict__ wob,
    const float* __restrict__ field, const float* __restrict__ strength,
    float* __restrict__ bias_out, float* __restrict__ energy_out)
{
    if (blockIdx.x == 4096) {
        int t = threadIdx.x;
        #pragma unroll
        for (int m = t; m < 1024; m += 256) {
            float acc = 0.f;
            #pragma unroll
            for (int o = 0; o < 3; ++o) {
                float s  = strength[o];
                float ph = 1.f / (1.f + __expf(-field[o * 1024 + m]));
                float tt = (float)(m * (o + 1)) * 3.14159265358979323846f / 1024.f;
                acc += s * sinf(tt) * ph;
            }
            bias_out[m] = acc;
        }
        if (t == 0) {
            float s0 = strength[0], s1 = strength[1], s2 = strength[2];
            energy_out[0] = (s0 * s0 + s1 * s1 + s2 * s2) * (1.f / 3.f);
        }
        return;
    }
    size_t g = (size_t)blockIdx.x * 256 + threadIdx.x;   // 0 .. 1048575
    size_t e = g * 8;
    const float* src; __bf16* dst; size_t off;
    if (e < 4194304) { src = x; dst = xb; off = e; }
    else {
        size_t t = e - 4194304;
        int w = (int)(t >> 20); off = t & 1048575;
        src = (w == 0 ? Wq : w == 1 ? Wk : w == 2 ? Wv : Wo);
        dst = (w == 0 ? wqb : w == 1 ? wkb : w == 2 ? wvb : wob);
    }
    float4 a = *(const float4*)(src + off);
    float4 b = *(const float4*)(src + off + 4);
    bf16x8 o;
    o[0] = (__bf16)a.x; o[1] = (__bf16)a.y; o[2] = (__bf16)a.z; o[3] = (__bf16)a.w;
    o[4] = (__bf16)b.x; o[5] = (__bf16)b.y; o[6] = (__bf16)b.z; o[7] = (__bf16)b.w;
    *(bf16x8*)(dst + off) = o;
}

// ---------------------------------------------------------------- NT GEMM (pipelined)
// C[m][n] = sum_k A[m][k] * Bt[n][k]  (+ bias[n]); M=4096, K=1024, N per grid.
// T3 2-phase double-buffered staging: tile t+1's global_load_lds fly under
// tile t's MFMA; vmcnt(0)+barrier only at phase top (never a mid-issue drain).
// MODE 0 (BN=128): z in {0,1,2} selects (Wq,bq)->q_ws, (Wk,bk)->k_ws, (Wv,bv)->vT_ws.
//   z==2 routes the C-tile through LDS (Cs, overlaid on dead staging bufs) so
//   the transposed vT write is coalesced dwordx4.
// MODE 1 (BN=64): Bt=B0, bias0, fp32 out; grid (16,32) -> 2 blocks/CU.
template <int MODE, int BN>
__global__ __launch_bounds__(256) void k_gemm(
    const __bf16* __restrict__ A,
    const __bf16* __restrict__ B0, const __bf16* __restrict__ B1, const __bf16* __restrict__ B2,
    const float* __restrict__ bias0, const float* __restrict__ bias1, const float* __restrict__ bias2,
    __bf16* __restrict__ q_ws, __bf16* __restrict__ k_ws, __bf16* __restrict__ vT_ws,
    float* __restrict__ out)
{
    const int K = 1024;
    constexpr int NB = BN / 32;            // 4 (BN=128) or 2 (BN=64)
    // staging: As0|As1 (4096 each) + Bs0|Bs1 (BN*32 each); Cs overlays all of
    // it after the K-loop (z==2 only; needs 17408 elems > 2*4096+2*4096=16384).
    __shared__ __bf16 smem[MODE == 0 ? 17408 : 12288];
    __bf16* As0 = smem;
    __bf16* As1 = smem + 4096;
    __bf16* Bs0 = smem + 8192;
    __bf16* Bs1 = Bs0 + BN * 32;
    __bf16* Cs  = smem;                    // valid only after final bar_nodrain

    int tid = threadIdx.x;
    int w = tid >> 6, l = tid & 63;
    int l15 = l & 15, quad = l >> 4;
    int m0 = blockIdx.y * 128, n0 = blockIdx.x * BN;
    int z = blockIdx.z;

    const __bf16* Bm = (MODE == 1) ? B0 : (z == 0 ? B0 : (z == 1 ? B1 : B2));
    const float*  bv = (MODE == 1) ? bias0 : (z == 0 ? bias0 : (z == 1 ? bias1 : bias2));

    int srow = w * 16 + (l >> 2);
    int scol = (l & 3) * 8;
    const __bf16* gA = A  + (size_t)(m0 + srow) * K + scol;
    const __bf16* gB = Bm + (size_t)(n0 + srow) * K + scol;

    f32x4 zero = {0.f, 0.f, 0.f, 0.f};
    f32x4 acc[4][NB];
    #pragma unroll
    for (int i = 0; i < 4; ++i)
        #pragma unroll
        for (int j = 0; j < NB; ++j) acc[i][j] = zero;

    int wm = w >> 1, wn = w & 1;

#define STAGE(bufA, bufB, kk)                                                  \
    do {                                                                       \
        GLDS16(gA + (kk),          (bufA) + w * 512);                          \
        GLDS16(gA + 64 * K + (kk), (bufA) + w * 512 + 2048);                   \
        GLDS16(gB + (kk),          (bufB) + w * 512);                          \
        if (BN == 128) GLDS16(gB + 64 * K + (kk), (bufB) + w * 512 + 2048);    \
    } while (0)

#define COMPUTE(bufA, bufB)                                                    \
    do {                                                                       \
        bf16x8 af[4], bfr[NB];                                                 \
        _Pragma("unroll")                                                      \
        for (int t = 0; t < 4; ++t)                                            \
            af[t] = *(const bf16x8*)&(bufA)[(wm * 64 + t * 16 + l15) * 32 + quad * 8]; \
        _Pragma("unroll")                                                      \
        for (int t = 0; t < NB; ++t)                                           \
            bfr[t] = *(const bf16x8*)&(bufB)[(wn * (BN / 2) + t * 16 + l15) * 32 + quad * 8]; \
        _Pragma("unroll")                                                      \
        for (int i = 0; i < 4; ++i)                                            \
            _Pragma("unroll")                                                  \
            for (int j = 0; j < NB; ++j)                                       \
                acc[i][j] = __builtin_amdgcn_mfma_f32_16x16x32_bf16(af[i], bfr[j], acc[i][j], 0, 0, 0); \
    } while (0)

    STAGE(As0, Bs0, 0);
    for (int k0 = 0; k0 < K; k0 += 64) {
        // phase A: compute buf0 tile k0, stage buf1 tile k0+32
        bar_wait_vm();                       // buf0's loads landed, all waves
        STAGE(As1, Bs1, k0 + 32);            // k0+32 < K always (K%64==0)
        COMPUTE(As0, Bs0);
        bar_nodrain();                       // all reads of buf0 done
        // phase B: compute buf1 tile k0+32, stage buf0 tile k0+64
        bar_wait_vm();
        if (k0 + 64 < K) STAGE(As0, Bs0, k0 + 64);
        COMPUTE(As1, Bs1);
        bar_nodrain();
    }
#undef STAGE
#undef COMPUTE

    if constexpr (MODE == 0) {
        if (z == 2) {
            // C fragment: row = m (quad*4+r), col = n (l15). Pack each lane's
            // 4 consecutive m into one b64 LDS write at Cs[n][m].
            #pragma unroll
            for (int j = 0; j < NB; ++j) {
                int nl = wn * 64 + j * 16 + l15;
                float badd = bv[n0 + nl];
                #pragma unroll
                for (int i = 0; i < 4; ++i) {
                    int ml = wm * 64 + i * 16 + quad * 4;
                    bf16x4 cv;
                    #pragma unroll
                    for (int r = 0; r < 4; ++r) cv[r] = (__bf16)(acc[i][j][r] + badd);
                    *(bf16x4*)&Cs[nl * 136 + ml] = cv;
                }
            }
            __syncthreads();
            // stream out: one (d, m-half) row per thread, 8 x dwordx4
            int row = tid >> 1;              // n_local 0..127
            int mh  = (tid & 1) * 64;        // m half
            int n = n0 + row, h = n >> 6, d = n & 63;
            int b = m0 >> 10;
            int lpos0 = m0 & 1023;           // position within the 1024-long L axis
            __bf16* drow = vT_ws + (((size_t)(b * 16 + h)) * 64 + d) * 1024 + lpos0 + mh;
            #pragma unroll
            for (int s2 = 0; s2 < 8; ++s2)
                *(int4*)&drow[s2 * 8] = *(const int4*)&Cs[row * 136 + mh + s2 * 8];
            return;
        }
    }

    // epilogue: C row = quad*4+r (m), col = l15 (n) within each 16x16 tile
    #pragma unroll
    for (int i = 0; i < 4; ++i) {
        int mbase = m0 + wm * 64 + i * 16 + quad * 4;
        #pragma unroll
        for (int j = 0; j < NB; ++j) {
            int n = n0 + wn * (BN / 2) + j * 16 + l15;
            float badd = bv[n];
            #pragma unroll
            for (int r = 0; r < 4; ++r) {
                int m = mbase + r;
                float vres = acc[i][j][r] + badd;
                if (MODE == 1) {
                    out[(size_t)m * 1024 + n] = vres;
                } else {
                    int b = m >> 10, lpos = m & 1023, h = n >> 6, d = n & 63;
                    __bf16* dst = (z == 0 ? q_ws : k_ws);
                    dst[(((size_t)(b * 16 + h)) * 1024 + lpos) * 64 + d] = (__bf16)vres;
                }
            }
        }
    }
}

// ---------------------------------------------------------------- attention
// grid (8 row-blocks, 64 bh); block 256 (4 waves, 2x2).
// SWAPPED QK^T: accT[j][i] = mfma(Kfrag, Qfrag) computes S^T fragments, so a
// lane holds 4 CONSECUTIVE kv for one q row -> b64 P_s writes, dwordx4 attn
// stores, float4 bias loads. Same arithmetic, same LDS reads as unswapped.
// pass 0: S -> p=exp -> rowsum(reg), P_s->LDS, O += P@V (unnormalized)
// pass 1: recompute S -> write attn = p * rowinv (once, 268 MB, coalesced)
__global__ __launch_bounds__(256, 2) void k_attn(
    const __bf16* __restrict__ qg, const __bf16* __restrict__ kg, const __bf16* __restrict__ vTg,
    const float* __restrict__ bias, float* __restrict__ attn, __bf16* __restrict__ Og)
{
    __shared__ __bf16 q_s[128 * 72];
    __shared__ __bf16 K_s[64 * 72];
    __shared__ __bf16 Vt_s[64 * 72];
    __shared__ __bf16 P_s[128 * 72];
    __shared__ float bias_s[1024];
    __shared__ float rowsum[128];
    __shared__ float rowinv[128];

    int tid = threadIdx.x, w = tid >> 6, l = tid & 63;
    int l15 = l & 15, quad = l >> 4;
    int wm = w >> 1, wn = w & 1;
    int bh = blockIdx.y;
    int m0 = blockIdx.x * 128;

    {   // q block 128x64 -> padded LDS (stride 72 breaks bank-aliasing)
        const __bf16* src = qg + ((size_t)bh * 1024 + m0) * 64;
        for (int i = tid; i < 1024; i += 256) {
            int r = i >> 3, c = (i & 7) * 8;
            *(int4*)&q_s[r * 72 + c] = *(const int4*)&src[(size_t)r * 64 + c];
        }
    }
    *(float4*)&bias_s[tid * 4] = *(const float4*)&bias[tid * 4];
    if (tid < 128) rowsum[tid] = 0.f;

    // staging coords: this thread owns K/V rows sr and sr+32, 16B at col sc
    int sr = tid >> 3;            // 0..31
    int sc = (tid & 7) * 8;       // 0..56
    const __bf16* kbase = kg  + (size_t)bh * 1024 * 64;
    const __bf16* vbase = vTg + (size_t)bh * 64 * 1024;

    // prefetch chunk 0
    int4 kr0 = *(const int4*)&kbase[(size_t)(sr)      * 64 + sc];
    int4 kr1 = *(const int4*)&kbase[(size_t)(sr + 32) * 64 + sc];
    int4 vr0 = *(const int4*)&vbase[(size_t)(sr)      * 1024 + sc];
    int4 vr1 = *(const int4*)&vbase[(size_t)(sr + 32) * 1024 + sc];

    f32x4 zero = {0.f, 0.f, 0.f, 0.f};
    f32x4 accO[4][2];
    #pragma unroll
    for (int i = 0; i < 4; ++i) { accO[i][0] = zero; accO[i][1] = zero; }
    float rs[4];
    #pragma unroll
    for (int i = 0; i < 4; ++i) rs[i] = 0.f;

    for (int pass = 0; pass < 2; ++pass) {
        for (int ch = 0; ch < 16; ++ch) {
            int n0c = ch * 64;
            bar_nodrain();   // prev chunk's LDS reads complete (also covers q_s init)
            *(int4*)&K_s[sr * 72 + sc]        = kr0;
            *(int4*)&K_s[(sr + 32) * 72 + sc] = kr1;
            if (pass == 0) {
                *(int4*)&Vt_s[sr * 72 + sc]        = vr0;
                *(int4*)&Vt_s[(sr + 32) * 72 + sc] = vr1;
            }
            bar_nodrain();   // staged data visible to all waves

            // issue next chunk's loads; they fly under this chunk's compute
            if (ch < 15) {
                int nn = n0c + 64;
                kr0 = *(const int4*)&kbase[(size_t)(nn + sr)      * 64 + sc];
                kr1 = *(const int4*)&kbase[(size_t)(nn + sr + 32) * 64 + sc];
                if (pass == 0) {
                    vr0 = *(const int4*)&vbase[(size_t)(sr)      * 1024 + nn + sc];
                    vr1 = *(const int4*)&vbase[(size_t)(sr + 32) * 1024 + nn + sc];
                }
            } else if (pass == 0) {   // prefetch pass-1 chunk 0 (K only)
                kr0 = *(const int4*)&kbase[(size_t)(sr)      * 64 + sc];
                kr1 = *(const int4*)&kbase[(size_t)(sr + 32) * 64 + sc];
            }

            // S^T fragments: rows = kv, cols(lanes) = q
            f32x4 accT[2][4];
            #pragma unroll
            for (int j = 0; j < 2; ++j)
                #pragma unroll
                for (int i = 0; i < 4; ++i) accT[j][i] = zero;
            __builtin_amdgcn_s_setprio(1);
            #pragma unroll
            for (int ks2 = 0; ks2 < 2; ++ks2) {
                bf16x8 qf[4], kf[2];
                #pragma unroll
                for (int t2 = 0; t2 < 4; ++t2)
                    qf[t2] = *(const bf16x8*)&q_s[(wm * 64 + t2 * 16 + l15) * 72 + ks2 * 32 + quad * 8];
                #pragma unroll
                for (int t2 = 0; t2 < 2; ++t2)
                    kf[t2] = *(const bf16x8*)&K_s[(wn * 32 + t2 * 16 + l15) * 72 + ks2 * 32 + quad * 8];
                #pragma unroll
                for (int j = 0; j < 2; ++j)
                    #pragma unroll
                    for (int i = 0; i < 4; ++i)
                        accT[j][i] = __builtin_amdgcn_mfma_f32_16x16x32_bf16(kf[j], qf[i], accT[j][i], 0, 0, 0);
            }
            __builtin_amdgcn_s_setprio(0);

            // bias along kv is now the register (row) axis: vector loads
            f32x4 b4[2];
            #pragma unroll
            for (int j = 0; j < 2; ++j)
                b4[j] = *(const f32x4*)&bias_s[n0c + wn * 32 + j * 16 + quad * 4];

            float p[4][2][4];   // [i=q-block][j=kv-block][r=kv within quad]
            #pragma unroll
            for (int i = 0; i < 4; ++i)
                #pragma unroll
                for (int j = 0; j < 2; ++j)
                    #pragma unroll
                    for (int r = 0; r < 4; ++r)
                        p[i][j][r] = __expf(0.125f * accT[j][i][r] + b4[j][r]);

            if (pass == 0) {
                #pragma unroll
                for (int i = 0; i < 4; ++i)
                    #pragma unroll
                    for (int j = 0; j < 2; ++j)
                        #pragma unroll
                        for (int r = 0; r < 4; ++r)
                            rs[i] += p[i][j][r];   // per-lane partial, reduce after loop
                #pragma unroll
                for (int i = 0; i < 4; ++i)
                    #pragma unroll
                    for (int j = 0; j < 2; ++j) {
                        bf16x4 pv;
                        #pragma unroll
                        for (int r = 0; r < 4; ++r) pv[r] = (__bf16)p[i][j][r];
                        *(bf16x4*)&P_s[(wm * 64 + i * 16 + l15) * 72 + wn * 32 + j * 16 + quad * 4] = pv;
                    }
                bar_nodrain();
                // O += P(128x64) @ V(64x64)
                __builtin_amdgcn_s_setprio(1);
                #pragma unroll
                for (int ks2 = 0; ks2 < 2; ++ks2) {
                    bf16x8 af[4], bfr[2];
                    #pragma unroll
                    for (int t2 = 0; t2 < 4; ++t2)
                        af[t2] = *(const bf16x8*)&P_s[(wm * 64 + t2 * 16 + l15) * 72 + ks2 * 32 + quad * 8];
                    #pragma unroll
                    for (int t2 = 0; t2 < 2; ++t2)
                        bfr[t2] = *(const bf16x8*)&Vt_s[(wn * 32 + t2 * 16 + l15) * 72 + ks2 * 32 + quad * 8];
                    #pragma unroll
                    for (int i = 0; i < 4; ++i)
                        #pragma unroll
                        for (int j = 0; j < 2; ++j)
                            accO[i][j] = __builtin_amdgcn_mfma_f32_16x16x32_bf16(af[i], bfr[j], accO[i][j], 0, 0, 0);
                }
                __builtin_amdgcn_s_setprio(0);
            } else {
                float* dst = attn + ((size_t)bh << 20) + (size_t)m0 * 1024;
                #pragma unroll
                for (int i = 0; i < 4; ++i) {
                    int q = wm * 64 + i * 16 + l15;
                    float inv = rowinv[q];
                    #pragma unroll
                    for (int j = 0; j < 2; ++j) {
                        float4 v;
                        v.x = p[i][j][0] * inv; v.y = p[i][j][1] * inv;
                        v.z = p[i][j][2] * inv; v.w = p[i][j][3] * inv;
                        *(float4*)&dst[(size_t)q * 1024 + n0c + wn * 32 + j * 16 + quad * 4] = v;
                    }
                }
            }
        }
        if (pass == 0) {
            // single rowsum reduction for all 16 chunks (sum across quads)
            #pragma unroll
            for (int i = 0; i < 4; ++i) {
                float s = rs[i];
                s += __shfl_xor(s, 16);
                s += __shfl_xor(s, 32);
                if (quad == 0) atomicAdd(&rowsum[wm * 64 + i * 16 + l15], s);
            }
            bar_nodrain();
            if (tid < 128) rowinv[tid] = 1.f / rowsum[tid];
            bar_nodrain();
            int b = bh >> 4, h = bh & 15;
            #pragma unroll
            for (int i = 0; i < 4; ++i)
                #pragma unroll
                for (int r = 0; r < 4; ++r) {
                    int row = wm * 64 + i * 16 + quad * 4 + r;
                    float inv = rowinv[row];
                    #pragma unroll
                    for (int j = 0; j < 2; ++j) {
                        int d = wn * 32 + j * 16 + l15;
                        Og[((size_t)(b * 1024 + m0 + row)) * 1024 + h * 64 + d] =
                            (__bf16)(accO[i][j][r] * inv);
                    }
                }
        }
    }
}

// ---------------------------------------------------------------- launch
extern "C" void kernel_launch(void* const* d_in, const int* in_sizes, int n_in,
                              void* d_out, int out_size, void* d_ws, size_t ws_size,
                              hipStream_t stream)
{
    const float* x  = (const float*)d_in[0];
    const float* Wq = (const float*)d_in[1];
    const float* bq = (const float*)d_in[2];
    const float* Wk = (const float*)d_in[3];
    const float* bk = (const float*)d_in[4];
    const float* Wv = (const float*)d_in[5];
    const float* bvv= (const float*)d_in[6];
    const float* Wo = (const float*)d_in[7];
    const float* bo = (const float*)d_in[8];
    const float* tf = (const float*)d_in[9];
    const float* ts = (const float*)d_in[10];

    float* out    = (float*)d_out;
    float* attn   = out + 4194304;           // (4,16,1024,1024)
    float* energy = attn + 67108864;         // scalar

    char* ws = (char*)d_ws;
    float*  bias  = (float*)ws;                                   //   4 KB
    __bf16* xb    = (__bf16*)(ws + 4096);                         // 8.4 MB (reused as O_ws)
    __bf16* wqb   = (__bf16*)(ws + 4096 + 8388608);               //   2 MB
    __bf16* wkb   = wqb + 1048576;
    __bf16* wvb   = wkb + 1048576;
    __bf16* wob   = wvb + 1048576;
    __bf16* q_ws  = wob + 1048576;                                // 8.4 MB
    __bf16* k_ws  = q_ws + 4194304;                               // 8.4 MB
    __bf16* vT_ws = k_ws + 4194304;                               // 8.4 MB
    __bf16* O_ws  = xb;   // x_bf dead after projections; reuse for O

    k_convert<<<dim3(4097), dim3(256), 0, stream>>>(x, Wq, Wk, Wv, Wo, xb, wqb, wkb, wvb, wob,
                                                    tf, ts, bias, energy);
    k_gemm<0, 128><<<dim3(8, 32, 3), dim3(256), 0, stream>>>(xb, wqb, wkb, wvb, bq, bk, bvv,
                                                             q_ws, k_ws, vT_ws, nullptr);
    k_attn<<<dim3(8, 64), dim3(256), 0, stream>>>(q_ws, k_ws, vT_ws, bias, attn, O_ws);
    k_gemm<1, 64><<<dim3(16, 32, 1), dim3(256), 0, stream>>>(O_ws, wob, nullptr, nullptr, bo,
                                                             nullptr, nullptr, nullptr, nullptr,
                                                             nullptr, out);
}

// Round 7
// 419.219 us; speedup vs baseline: 1.1137x; 1.0209x over previous
//
#include <hip/hip_runtime.h>
#include <hip/hip_bf16.h>

typedef __bf16 bf16x8 __attribute__((ext_vector_type(8)));
typedef __bf16 bf16x4 __attribute__((ext_vector_type(4)));
typedef float f32x4 __attribute__((ext_vector_type(4)));

#define GLDS16(gp, lp) \
    __builtin_amdgcn_global_load_lds((__attribute__((address_space(1))) void*)(gp), \
                                     (__attribute__((address_space(3))) void*)(lp), 16, 0, 0)

// Barrier that does NOT drain vmcnt: lets prefetched global loads stay in
// flight across the sync (ds ordering still guaranteed via lgkmcnt(0)).
static __device__ __forceinline__ void bar_nodrain() {
    __builtin_amdgcn_sched_barrier(0);
    asm volatile("s_waitcnt lgkmcnt(0)" ::: "memory");
    __builtin_amdgcn_s_barrier();
    __builtin_amdgcn_sched_barrier(0);
}

// Barrier that waits for THIS wave's outstanding global(_load_lds) ops, then
// syncs: after it, every wave's staged LDS data is visible to all.
static __device__ __forceinline__ void bar_wait_vm() {
    __builtin_amdgcn_sched_barrier(0);
    asm volatile("s_waitcnt vmcnt(0)" ::: "memory");
    __builtin_amdgcn_s_barrier();
    __builtin_amdgcn_sched_barrier(0);
}

// ---------------------------------------------------------------- convert (+ fused bias/energy)
// blocks 0..4095: x (4M floats) and Wq/Wk/Wv/Wo (1M each) -> bf16 copies in ws.
// block 4096: torsion bias vector + energy scalar.
__global__ __launch_bounds__(256) void k_convert(
    const float* __restrict__ x, const float* __restrict__ Wq,
    const float* __restrict__ Wk, const float* __restrict__ Wv,
    const float* __restrict__ Wo,
    __bf16* __restrict__ xb, __bf16* __restrict__ wqb, __bf16* __restrict__ wkb,
    __bf16* __restrict__ wvb, __bf16* __restrict__ wob,
    const float* __restrict__ field, const float* __restrict__ strength,
    float* __restrict__ bias_out, float* __restrict__ energy_out)
{
    if (blockIdx.x == 4096) {
        int t = threadIdx.x;
        #pragma unroll
        for (int m = t; m < 1024; m += 256) {
            float acc = 0.f;
            #pragma unroll
            for (int o = 0; o < 3; ++o) {
                float s  = strength[o];
                float ph = 1.f / (1.f + __expf(-field[o * 1024 + m]));
                float tt = (float)(m * (o + 1)) * 3.14159265358979323846f / 1024.f;
                acc += s * sinf(tt) * ph;
            }
            bias_out[m] = acc;
        }
        if (t == 0) {
            float s0 = strength[0], s1 = strength[1], s2 = strength[2];
            energy_out[0] = (s0 * s0 + s1 * s1 + s2 * s2) * (1.f / 3.f);
        }
        return;
    }
    size_t g = (size_t)blockIdx.x * 256 + threadIdx.x;   // 0 .. 1048575
    size_t e = g * 8;
    const float* src; __bf16* dst; size_t off;
    if (e < 4194304) { src = x; dst = xb; off = e; }
    else {
        size_t t = e - 4194304;
        int w = (int)(t >> 20); off = t & 1048575;
        src = (w == 0 ? Wq : w == 1 ? Wk : w == 2 ? Wv : Wo);
        dst = (w == 0 ? wqb : w == 1 ? wkb : w == 2 ? wvb : wob);
    }
    float4 a = *(const float4*)(src + off);
    float4 b = *(const float4*)(src + off + 4);
    bf16x8 o;
    o[0] = (__bf16)a.x; o[1] = (__bf16)a.y; o[2] = (__bf16)a.z; o[3] = (__bf16)a.w;
    o[4] = (__bf16)b.x; o[5] = (__bf16)b.y; o[6] = (__bf16)b.z; o[7] = (__bf16)b.w;
    *(bf16x8*)(dst + off) = o;
}

// ---------------------------------------------------------------- NT GEMM (pipelined)
// C[m][n] = sum_k A[m][k] * Bt[n][k]  (+ bias[n]); M=4096, K=1024, N per grid.
// T3 2-phase double-buffered staging: tile t+1's global_load_lds fly under
// tile t's MFMA; vmcnt(0)+barrier only at phase top (never a mid-issue drain).
// MODE 0 (BN=128): z in {0,1,2} selects (Wq,bq)->q_ws, (Wk,bk)->k_ws, (Wv,bv)->vT_ws.
//   Default dispatch order already n-aligns blocks with XCDs (gridDim.x=8):
//   each XCD keeps one B-panel L2-resident — no swizzle needed.
//   z==2 routes the C-tile through LDS (Cs, overlaid on dead staging bufs) so
//   the transposed vT write is coalesced dwordx4.
// MODE 1 (BN=64): grid (16,32); XCD m-clustering: each XCD owns 4 m-panels x
//   16 n-blocks so A (1 MB) + B (2 MB) are L2-resident after first touch.
template <int MODE, int BN>
__global__ __launch_bounds__(256) void k_gemm(
    const __bf16* __restrict__ A,
    const __bf16* __restrict__ B0, const __bf16* __restrict__ B1, const __bf16* __restrict__ B2,
    const float* __restrict__ bias0, const float* __restrict__ bias1, const float* __restrict__ bias2,
    __bf16* __restrict__ q_ws, __bf16* __restrict__ k_ws, __bf16* __restrict__ vT_ws,
    float* __restrict__ out)
{
    const int K = 1024;
    constexpr int NB = BN / 32;            // 4 (BN=128) or 2 (BN=64)
    // staging: As0|As1 (4096 each) + Bs0|Bs1 (BN*32 each); Cs overlays all of
    // it after the K-loop (z==2 only; needs 17408 elems > 2*4096+2*4096=16384).
    __shared__ __bf16 smem[MODE == 0 ? 17408 : 12288];
    __bf16* As0 = smem;
    __bf16* As1 = smem + 4096;
    __bf16* Bs0 = smem + 8192;
    __bf16* Bs1 = Bs0 + BN * 32;
    __bf16* Cs  = smem;                    // valid only after final bar_nodrain

    int tid = threadIdx.x;
    int w = tid >> 6, l = tid & 63;
    int l15 = l & 15, quad = l >> 4;

    int bx = blockIdx.x, by = blockIdx.y;
    if constexpr (MODE == 1) {
        // XCD m-clustering (bijective): xcd = lin&7 heuristic; each XCD gets
        // m-panels [xcd*4, xcd*4+4) x all 16 n-blocks.
        int lin = by * 16 + bx;            // 0..511
        int xcd = lin & 7, t = lin >> 3;   // t 0..63
        by = xcd * 4 + (t >> 4);           // m-panel 0..31
        bx = t & 15;                       // n-block 0..15
    }
    int m0 = by * 128, n0 = bx * BN;
    int z = blockIdx.z;

    const __bf16* Bm = (MODE == 1) ? B0 : (z == 0 ? B0 : (z == 1 ? B1 : B2));
    const float*  bv = (MODE == 1) ? bias0 : (z == 0 ? bias0 : (z == 1 ? bias1 : bias2));

    int srow = w * 16 + (l >> 2);
    int scol = (l & 3) * 8;
    const __bf16* gA = A  + (size_t)(m0 + srow) * K + scol;
    const __bf16* gB = Bm + (size_t)(n0 + srow) * K + scol;

    f32x4 zero = {0.f, 0.f, 0.f, 0.f};
    f32x4 acc[4][NB];
    #pragma unroll
    for (int i = 0; i < 4; ++i)
        #pragma unroll
        for (int j = 0; j < NB; ++j) acc[i][j] = zero;

    int wm = w >> 1, wn = w & 1;

#define STAGE(bufA, bufB, kk)                                                  \
    do {                                                                       \
        GLDS16(gA + (kk),          (bufA) + w * 512);                          \
        GLDS16(gA + 64 * K + (kk), (bufA) + w * 512 + 2048);                   \
        GLDS16(gB + (kk),          (bufB) + w * 512);                          \
        if (BN == 128) GLDS16(gB + 64 * K + (kk), (bufB) + w * 512 + 2048);    \
    } while (0)

#define COMPUTE(bufA, bufB)                                                    \
    do {                                                                       \
        bf16x8 af[4], bfr[NB];                                                 \
        _Pragma("unroll")                                                      \
        for (int t = 0; t < 4; ++t)                                            \
            af[t] = *(const bf16x8*)&(bufA)[(wm * 64 + t * 16 + l15) * 32 + quad * 8]; \
        _Pragma("unroll")                                                      \
        for (int t = 0; t < NB; ++t)                                           \
            bfr[t] = *(const bf16x8*)&(bufB)[(wn * (BN / 2) + t * 16 + l15) * 32 + quad * 8]; \
        _Pragma("unroll")                                                      \
        for (int i = 0; i < 4; ++i)                                            \
            _Pragma("unroll")                                                  \
            for (int j = 0; j < NB; ++j)                                       \
                acc[i][j] = __builtin_amdgcn_mfma_f32_16x16x32_bf16(af[i], bfr[j], acc[i][j], 0, 0, 0); \
    } while (0)

    STAGE(As0, Bs0, 0);
    for (int k0 = 0; k0 < K; k0 += 64) {
        // phase A: compute buf0 tile k0, stage buf1 tile k0+32
        bar_wait_vm();                       // buf0's loads landed, all waves
        STAGE(As1, Bs1, k0 + 32);            // k0+32 < K always (K%64==0)
        COMPUTE(As0, Bs0);
        bar_nodrain();                       // all reads of buf0 done
        // phase B: compute buf1 tile k0+32, stage buf0 tile k0+64
        bar_wait_vm();
        if (k0 + 64 < K) STAGE(As0, Bs0, k0 + 64);
        COMPUTE(As1, Bs1);
        bar_nodrain();
    }
#undef STAGE
#undef COMPUTE

    if constexpr (MODE == 0) {
        if (z == 2) {
            // C fragment: row = m (quad*4+r), col = n (l15). Pack each lane's
            // 4 consecutive m into one b64 LDS write at Cs[n][m].
            #pragma unroll
            for (int j = 0; j < NB; ++j) {
                int nl = wn * 64 + j * 16 + l15;
                float badd = bv[n0 + nl];
                #pragma unroll
                for (int i = 0; i < 4; ++i) {
                    int ml = wm * 64 + i * 16 + quad * 4;
                    bf16x4 cv;
                    #pragma unroll
                    for (int r = 0; r < 4; ++r) cv[r] = (__bf16)(acc[i][j][r] + badd);
                    *(bf16x4*)&Cs[nl * 136 + ml] = cv;
                }
            }
            __syncthreads();
            // stream out: one (d, m-half) row per thread, 8 x dwordx4
            int row = tid >> 1;              // n_local 0..127
            int mh  = (tid & 1) * 64;        // m half
            int n = n0 + row, h = n >> 6, d = n & 63;
            int b = m0 >> 10;
            int lpos0 = m0 & 1023;           // position within the 1024-long L axis
            __bf16* drow = vT_ws + (((size_t)(b * 16 + h)) * 64 + d) * 1024 + lpos0 + mh;
            #pragma unroll
            for (int s2 = 0; s2 < 8; ++s2)
                *(int4*)&drow[s2 * 8] = *(const int4*)&Cs[row * 136 + mh + s2 * 8];
            return;
        }
    }

    // epilogue: C row = quad*4+r (m), col = l15 (n) within each 16x16 tile
    #pragma unroll
    for (int i = 0; i < 4; ++i) {
        int mbase = m0 + wm * 64 + i * 16 + quad * 4;
        #pragma unroll
        for (int j = 0; j < NB; ++j) {
            int n = n0 + wn * (BN / 2) + j * 16 + l15;
            float badd = bv[n];
            #pragma unroll
            for (int r = 0; r < 4; ++r) {
                int m = mbase + r;
                float vres = acc[i][j][r] + badd;
                if (MODE == 1) {
                    out[(size_t)m * 1024 + n] = vres;
                } else {
                    int b = m >> 10, lpos = m & 1023, h = n >> 6, d = n & 63;
                    __bf16* dst = (z == 0 ? q_ws : k_ws);
                    dst[(((size_t)(b * 16 + h)) * 1024 + lpos) * 64 + d] = (__bf16)vres;
                }
            }
        }
    }
}

// ---------------------------------------------------------------- attention
// grid (8 row-blocks, 64 bh); block 256 (4 waves, 2x2).
// XCD bh-clustering: xcd = lin&7 heuristic; each XCD owns 8 whole bh's
// (K/V working set 1.5 MB << 4 MB L2) so the 16 re-reads per bh (8 row-blocks
// x 2 passes) hit the local L2 instead of L3.
// SWAPPED QK^T: accT[j][i] = mfma(Kfrag, Qfrag) computes S^T fragments, so a
// lane holds 4 CONSECUTIVE kv for one q row -> b64 P_s writes, dwordx4 attn
// stores, float4 bias loads. Same arithmetic, same LDS reads as unswapped.
// pass 0: S -> p=exp -> rowsum(reg), P_s->LDS, O += P@V (unnormalized)
// pass 1: recompute S -> write attn = p * rowinv (once, 268 MB, coalesced)
__global__ __launch_bounds__(256, 2) void k_attn(
    const __bf16* __restrict__ qg, const __bf16* __restrict__ kg, const __bf16* __restrict__ vTg,
    const float* __restrict__ bias, float* __restrict__ attn, __bf16* __restrict__ Og)
{
    __shared__ __bf16 q_s[128 * 72];
    __shared__ __bf16 K_s[64 * 72];
    __shared__ __bf16 Vt_s[64 * 72];
    __shared__ __bf16 P_s[128 * 72];
    __shared__ float bias_s[1024];
    __shared__ float rowsum[128];
    __shared__ float rowinv[128];

    int tid = threadIdx.x, w = tid >> 6, l = tid & 63;
    int l15 = l & 15, quad = l >> 4;
    int wm = w >> 1, wn = w & 1;

    // XCD-clustered work assignment (bijective remap of (x,y))
    int lin = blockIdx.y * 8 + blockIdx.x;   // 0..511, xcd = lin&7 heuristic
    int xcd = lin & 7, tt0 = lin >> 3;       // tt0 0..63
    int bh  = xcd * 8 + (tt0 >> 3);          // 8 bh per XCD
    int m0  = (tt0 & 7) * 128;               // 8 row-blocks per bh

    {   // q block 128x64 -> padded LDS (stride 72 breaks bank-aliasing)
        const __bf16* src = qg + ((size_t)bh * 1024 + m0) * 64;
        for (int i = tid; i < 1024; i += 256) {
            int r = i >> 3, c = (i & 7) * 8;
            *(int4*)&q_s[r * 72 + c] = *(const int4*)&src[(size_t)r * 64 + c];
        }
    }
    *(float4*)&bias_s[tid * 4] = *(const float4*)&bias[tid * 4];
    if (tid < 128) rowsum[tid] = 0.f;

    // staging coords: this thread owns K/V rows sr and sr+32, 16B at col sc
    int sr = tid >> 3;            // 0..31
    int sc = (tid & 7) * 8;       // 0..56
    const __bf16* kbase = kg  + (size_t)bh * 1024 * 64;
    const __bf16* vbase = vTg + (size_t)bh * 64 * 1024;

    // prefetch chunk 0
    int4 kr0 = *(const int4*)&kbase[(size_t)(sr)      * 64 + sc];
    int4 kr1 = *(const int4*)&kbase[(size_t)(sr + 32) * 64 + sc];
    int4 vr0 = *(const int4*)&vbase[(size_t)(sr)      * 1024 + sc];
    int4 vr1 = *(const int4*)&vbase[(size_t)(sr + 32) * 1024 + sc];

    f32x4 zero = {0.f, 0.f, 0.f, 0.f};
    f32x4 accO[4][2];
    #pragma unroll
    for (int i = 0; i < 4; ++i) { accO[i][0] = zero; accO[i][1] = zero; }
    float rs[4];
    #pragma unroll
    for (int i = 0; i < 4; ++i) rs[i] = 0.f;
    float inv_r[4] = {0.f, 0.f, 0.f, 0.f};   // set after pass 0

    for (int pass = 0; pass < 2; ++pass) {
        for (int ch = 0; ch < 16; ++ch) {
            int n0c = ch * 64;
            bar_nodrain();   // prev chunk's LDS reads complete (also covers q_s init)
            *(int4*)&K_s[sr * 72 + sc]        = kr0;
            *(int4*)&K_s[(sr + 32) * 72 + sc] = kr1;
            if (pass == 0) {
                *(int4*)&Vt_s[sr * 72 + sc]        = vr0;
                *(int4*)&Vt_s[(sr + 32) * 72 + sc] = vr1;
            }
            bar_nodrain();   // staged data visible to all waves

            // issue next chunk's loads; they fly under this chunk's compute
            if (ch < 15) {
                int nn = n0c + 64;
                kr0 = *(const int4*)&kbase[(size_t)(nn + sr)      * 64 + sc];
                kr1 = *(const int4*)&kbase[(size_t)(nn + sr + 32) * 64 + sc];
                if (pass == 0) {
                    vr0 = *(const int4*)&vbase[(size_t)(sr)      * 1024 + nn + sc];
                    vr1 = *(const int4*)&vbase[(size_t)(sr + 32) * 1024 + nn + sc];
                }
            } else if (pass == 0) {   // prefetch pass-1 chunk 0 (K only)
                kr0 = *(const int4*)&kbase[(size_t)(sr)      * 64 + sc];
                kr1 = *(const int4*)&kbase[(size_t)(sr + 32) * 64 + sc];
            }

            // S^T fragments: rows = kv, cols(lanes) = q
            f32x4 accT[2][4];
            #pragma unroll
            for (int j = 0; j < 2; ++j)
                #pragma unroll
                for (int i = 0; i < 4; ++i) accT[j][i] = zero;
            __builtin_amdgcn_s_setprio(1);
            #pragma unroll
            for (int ks2 = 0; ks2 < 2; ++ks2) {
                bf16x8 qf[4], kf[2];
                #pragma unroll
                for (int t2 = 0; t2 < 4; ++t2)
                    qf[t2] = *(const bf16x8*)&q_s[(wm * 64 + t2 * 16 + l15) * 72 + ks2 * 32 + quad * 8];
                #pragma unroll
                for (int t2 = 0; t2 < 2; ++t2)
                    kf[t2] = *(const bf16x8*)&K_s[(wn * 32 + t2 * 16 + l15) * 72 + ks2 * 32 + quad * 8];
                #pragma unroll
                for (int j = 0; j < 2; ++j)
                    #pragma unroll
                    for (int i = 0; i < 4; ++i)
                        accT[j][i] = __builtin_amdgcn_mfma_f32_16x16x32_bf16(kf[j], qf[i], accT[j][i], 0, 0, 0);
            }
            __builtin_amdgcn_s_setprio(0);

            // bias along kv is now the register (row) axis: vector loads
            f32x4 b4[2];
            #pragma unroll
            for (int j = 0; j < 2; ++j)
                b4[j] = *(const f32x4*)&bias_s[n0c + wn * 32 + j * 16 + quad * 4];

            float p[4][2][4];   // [i=q-block][j=kv-block][r=kv within quad]
            #pragma unroll
            for (int i = 0; i < 4; ++i)
                #pragma unroll
                for (int j = 0; j < 2; ++j)
                    #pragma unroll
                    for (int r = 0; r < 4; ++r)
                        p[i][j][r] = __expf(0.125f * accT[j][i][r] + b4[j][r]);

            if (pass == 0) {
                #pragma unroll
                for (int i = 0; i < 4; ++i)
                    #pragma unroll
                    for (int j = 0; j < 2; ++j)
                        #pragma unroll
                        for (int r = 0; r < 4; ++r)
                            rs[i] += p[i][j][r];   // per-lane partial, reduce after loop
                #pragma unroll
                for (int i = 0; i < 4; ++i)
                    #pragma unroll
                    for (int j = 0; j < 2; ++j) {
                        bf16x4 pv;
                        #pragma unroll
                        for (int r = 0; r < 4; ++r) pv[r] = (__bf16)p[i][j][r];
                        *(bf16x4*)&P_s[(wm * 64 + i * 16 + l15) * 72 + wn * 32 + j * 16 + quad * 4] = pv;
                    }
                bar_nodrain();
                // O += P(128x64) @ V(64x64)
                __builtin_amdgcn_s_setprio(1);
                #pragma unroll
                for (int ks2 = 0; ks2 < 2; ++ks2) {
                    bf16x8 af[4], bfr[2];
                    #pragma unroll
                    for (int t2 = 0; t2 < 4; ++t2)
                        af[t2] = *(const bf16x8*)&P_s[(wm * 64 + t2 * 16 + l15) * 72 + ks2 * 32 + quad * 8];
                    #pragma unroll
                    for (int t2 = 0; t2 < 2; ++t2)
                        bfr[t2] = *(const bf16x8*)&Vt_s[(wn * 32 + t2 * 16 + l15) * 72 + ks2 * 32 + quad * 8];
                    #pragma unroll
                    for (int i = 0; i < 4; ++i)
                        #pragma unroll
                        for (int j = 0; j < 2; ++j)
                            accO[i][j] = __builtin_amdgcn_mfma_f32_16x16x32_bf16(af[i], bfr[j], accO[i][j], 0, 0, 0);
                }
                __builtin_amdgcn_s_setprio(0);
            } else {
                float* dst = attn + ((size_t)bh << 20) + (size_t)m0 * 1024;
                #pragma unroll
                for (int i = 0; i < 4; ++i) {
                    int q = wm * 64 + i * 16 + l15;
                    float inv = inv_r[i];
                    #pragma unroll
                    for (int j = 0; j < 2; ++j) {
                        float4 v;
                        v.x = p[i][j][0] * inv; v.y = p[i][j][1] * inv;
                        v.z = p[i][j][2] * inv; v.w = p[i][j][3] * inv;
                        *(float4*)&dst[(size_t)q * 1024 + n0c + wn * 32 + j * 16 + quad * 4] = v;
                    }
                }
            }
        }
        if (pass == 0) {
            // single rowsum reduction for all 16 chunks (sum across quads)
            #pragma unroll
            for (int i = 0; i < 4; ++i) {
                float s = rs[i];
                s += __shfl_xor(s, 16);
                s += __shfl_xor(s, 32);
                if (quad == 0) atomicAdd(&rowsum[wm * 64 + i * 16 + l15], s);
            }
            bar_nodrain();
            if (tid < 128) rowinv[tid] = 1.f / rowsum[tid];
            bar_nodrain();
            // hoist pass-1 normalizers into registers (chunk-invariant)
            #pragma unroll
            for (int i = 0; i < 4; ++i) inv_r[i] = rowinv[wm * 64 + i * 16 + l15];
            int b = bh >> 4, h = bh & 15;
            #pragma unroll
            for (int i = 0; i < 4; ++i)
                #pragma unroll
                for (int r = 0; r < 4; ++r) {
                    int row = wm * 64 + i * 16 + quad * 4 + r;
                    float inv = rowinv[row];
                    #pragma unroll
                    for (int j = 0; j < 2; ++j) {
                        int d = wn * 32 + j * 16 + l15;
                        Og[((size_t)(b * 1024 + m0 + row)) * 1024 + h * 64 + d] =
                            (__bf16)(accO[i][j][r] * inv);
                    }
                }
        }
    }
}

// ---------------------------------------------------------------- launch
extern "C" void kernel_launch(void* const* d_in, const int* in_sizes, int n_in,
                              void* d_out, int out_size, void* d_ws, size_t ws_size,
                              hipStream_t stream)
{
    const float* x  = (const float*)d_in[0];
    const float* Wq = (const float*)d_in[1];
    const float* bq = (const float*)d_in[2];
    const float* Wk = (const float*)d_in[3];
    const float* bk = (const float*)d_in[4];
    const float* Wv = (const float*)d_in[5];
    const float* bvv= (const float*)d_in[6];
    const float* Wo = (const float*)d_in[7];
    const float* bo = (const float*)d_in[8];
    const float* tf = (const float*)d_in[9];
    const float* ts = (const float*)d_in[10];

    float* out    = (float*)d_out;
    float* attn   = out + 4194304;           // (4,16,1024,1024)
    float* energy = attn + 67108864;         // scalar

    char* ws = (char*)d_ws;
    float*  bias  = (float*)ws;                                   //   4 KB
    __bf16* xb    = (__bf16*)(ws + 4096);                         // 8.4 MB (reused as O_ws)
    __bf16* wqb   = (__bf16*)(ws + 4096 + 8388608);               //   2 MB
    __bf16* wkb   = wqb + 1048576;
    __bf16* wvb   = wkb + 1048576;
    __bf16* wob   = wvb + 1048576;
    __bf16* q_ws  = wob + 1048576;                                // 8.4 MB
    __bf16* k_ws  = q_ws + 4194304;                               // 8.4 MB
    __bf16* vT_ws = k_ws + 4194304;                               // 8.4 MB
    __bf16* O_ws  = xb;   // x_bf dead after projections; reuse for O

    k_convert<<<dim3(4097), dim3(256), 0, stream>>>(x, Wq, Wk, Wv, Wo, xb, wqb, wkb, wvb, wob,
                                                    tf, ts, bias, energy);
    k_gemm<0, 128><<<dim3(8, 32, 3), dim3(256), 0, stream>>>(xb, wqb, wkb, wvb, bq, bk, bvv,
                                                             q_ws, k_ws, vT_ws, nullptr);
    k_attn<<<dim3(8, 64), dim3(256), 0, stream>>>(q_ws, k_ws, vT_ws, bias, attn, O_ws);
    k_gemm<1, 64><<<dim3(16, 32, 1), dim3(256), 0, stream>>>(O_ws, wob, nullptr, nullptr, bo,
                                                             nullptr, nullptr, nullptr, nullptr,
                                                             nullptr, out);
}